// Round 2
// baseline (283.380 us; speedup 1.0000x reference)
//
#include <hip/hip_runtime.h>
#include <math.h>

// SSM_18597208391915: HiPPO-LegT recurrence, O(N) semiseparable solve.
// Ad = (I-cA)^{-1}(I+cA) = 2M - I  =>  h' = tanh(2*M(h + c*u*P) - h).
// R12: occupancy re-tile. R11 post-mortem: 15% inst cut gave only 2.3% time
// -> latency-bound on the serial per-step chain, not issue-bound. Fix: NW=8
// waves x EPL=2 (512-thr blocks, 512 blocks -> 2 blocks/CU = 4 waves/SIMD,
// 2x the independent chains per SIMD). Total issue/step unchanged
// (8x~29 inst vs 4x~56). Enablers:
//   (1) composed-stream publish: wave w publishes Tot_w = Bacc + Phi_w*Tin
//       (1 fma per value, lane 63 only), so every wave reads exactly ONE
//       stream Tin = tot_s[wv-1] regardless of NW. Algebraically equal to
//       the R11 cin-coefficient composition.
//   (2) EPL=2 shrinks the lane-local triangle to t10 and the shared-rcp
//       group to a pair (1 v_rcp per 2 sigmoids).
// R11 mechanics retained: m = c2*h state, flattened g, bound_ctrl DPP scan,
// 16-step register inner loop, one barrier per chunk, float4 LDS comms.

#define SEQ     784
#define OUT_DIM 10
#define NW      8
#define CH      16            // steps per chunk
#define NCH     (SEQ/CH)      // 49
#define EPL     2             // elems/lane: NW*64*EPL = 1024 = HIDDEN

#if __has_builtin(__builtin_amdgcn_exp2f)
#define EXP2F(x) __builtin_amdgcn_exp2f(x)
#else
#define EXP2F(x) __expf(0.69314718055994531f * (x))
#endif

// DPP move with explicit old: masked/invalid lanes get `old`.
template<int CTRL, int ROW_MASK>
__device__ __forceinline__ float dpp_mov(float src, float old) {
    return __int_as_float(__builtin_amdgcn_update_dpp(
        __float_as_int(old), __float_as_int(src), CTRL, ROW_MASK, 0xf, false));
}
// DPP move, bound_ctrl:0 — invalid lanes read 0, full row/bank mask.
template<int CTRL>
__device__ __forceinline__ float dpp_bc0(float src) {
    return __int_as_float(__builtin_amdgcn_update_dpp(
        0, __float_as_int(src), CTRL, 0xf, 0xf, true));
}
// ctrls: row_shr:N = 0x110|N, row_bcast15 = 0x142, row_bcast31 = 0x143,
//        wave_shr:1 = 0x138

__global__ __launch_bounds__(512, 4)
void ssm_hippo_scan(const float* __restrict__ x,     // (512, 784)
                    const float* __restrict__ C,     // (1024)
                    const float* __restrict__ W,     // (10)
                    const float* __restrict__ bvec,  // (10)
                    float* __restrict__ out)         // (512, 10)
{
    const int b    = blockIdx.x;
    const int tid  = threadIdx.x;
    const int wv   = tid >> 6;       // wave w owns elems [w*128, w*128+128)
    const int lane = tid & 63;

    __shared__ __align__(16) float u_s[SEQ];
    __shared__ __align__(16) float tot_s[NW-1][SEQ]; // composed B-totals
    __shared__ double part_s[NW];

    for (int t = tid; t < SEQ; t += 512) u_s[t] = x[b * SEQ + t];

    const double hdt  = 0.5 / (double)SEQ;            // c = dt/2
    const double L2E2 = 2.0 * 1.4426950408889634;     // 2*log2(e)

    // ---- per-element constants (n = wv*128 + lane*2 + i), fp64-derived.
    // Recurrence in exponent space (w = m + upc*u, m = c2*h):
    //   S_{n+1} = alpha_n S_n + pdin_n w_n ; g_n = ivd_n w_n - m_n - hp_n S_n
    float upc0, upc1, ivd0, ivd1, ka0, ka1, cB0, cB1, t10;
    float Alev0, Alev1, Alev2, Alev3, Alev4, Alev5, Aexcl;
    float PhiW, c2, n2c2;
    {
        const int n0 = wv * 128 + lane * 2;
        const int n1 = n0 + 1;
        const double p0 = sqrt(1.0 + 2.0 * (double)n0);
        const double p1 = sqrt(1.0 + 2.0 * (double)n1);
        const double d0 = 1.0 + hdt * (double)(n0 + 1);
        const double d1 = 1.0 + hdt * (double)(n1 + 1);
        const double a0 = 1.0 - hdt * p0 * p0 / d0;
        const double a1 = 1.0 - hdt * p1 * p1 / d1;
        const double pdin0 = p0 / d0, pdin1 = p1 / d1;
        const double hp0 = 2.0 * hdt * p0 / d0;
        const double hp1 = 2.0 * hdt * p1 / d1;
        upc0 = (float)(L2E2 * hdt * p0);
        upc1 = (float)(L2E2 * hdt * p1);
        ivd0 = (float)(2.0 / d0);
        ivd1 = (float)(2.0 / d1);
        ka0  = (float)(-hp0);
        ka1  = (float)(-hp1 * a0);
        cB0  = (float)(a1 * pdin0);
        cB1  = (float)(pdin1);
        t10  = (float)(-hp1 * pdin0);

        float A = (float)(a0 * a1);               // per-lane decay
        Alev0 = A; A *= dpp_mov<0x111, 0xf>(A, 1.0f);
        Alev1 = A; A *= dpp_mov<0x112, 0xf>(A, 1.0f);
        Alev2 = A; A *= dpp_mov<0x114, 0xf>(A, 1.0f);
        Alev3 = A; A *= dpp_mov<0x118, 0xf>(A, 1.0f);
        Alev4 = A; A *= dpp_mov<0x142, 0xa>(A, 1.0f);
        Alev5 = A; A *= dpp_mov<0x143, 0xc>(A, 1.0f);
        Aexcl = dpp_mov<0x138, 0xf>(A, 1.0f);     // lane0 -> 1 (excl prod)

        // own wave's total decay Phi (closed form, fp64):
        // alpha_n = (1 - hdt*n) / (1 + hdt*(n+1))
        double np = 1.0, dp = 1.0;
        for (int n = wv * 128; n < wv * 128 + 128; ++n) {
            np *= 1.0 - hdt * (double)n;
            dp *= 1.0 + hdt * (double)(n + 1);
        }
        PhiW = (float)(np / dp);

        c2   = (float)L2E2;
        n2c2 = (float)(-2.0 * L2E2);
    }

    __syncthreads();                         // u_s ready

    // ---- state: m = c2 * h   (h = 0 -> m = 0)
    float m0 = 0.0f, m1 = 0.0f;

#pragma unroll 1
    for (int tick = 0; tick < NCH + NW - 1; ++tick) {
        const int ch = tick - wv;            // this wave's chunk index
        if (0 <= ch && ch < NCH) {
            // ---- bulk register loads: u's and the one incoming stream
            float4 u4[CH/4];
            float  Tin[CH];
            {
                const float4* up = (const float4*)&u_s[ch * CH];
#pragma unroll
                for (int q = 0; q < CH/4; ++q) u4[q] = up[q];
            }
            if (wv == 0) {
#pragma unroll
                for (int k = 0; k < CH; ++k) Tin[k] = 0.0f;
            } else {
                const float4* b0 = (const float4*)&tot_s[wv - 1][ch * CH];
#pragma unroll
                for (int q = 0; q < CH/4; ++q) {
                    const float4 v0 = b0[q];
                    Tin[4*q+0] = v0.x; Tin[4*q+1] = v0.y;
                    Tin[4*q+2] = v0.z; Tin[4*q+3] = v0.w;
                }
            }
            float Bacc[CH];

#pragma unroll
            for (int k = 0; k < CH; ++k) {
                const float u = ((const float*)&u4[k>>2])[k&3];

                // ---- head: w_i = upc_i*u + m_i
                const float w0 = fmaf(upc0, u, m0);
                const float w1 = fmaf(upc1, u, m1);

                // ---- lane-inclusive affine-B
                float B = fmaf(cB0, w0, cB1 * w1);

                // ---- cross-lane affine scan (A's precomputed)
                float Bin;
                Bin = dpp_bc0<0x111>(B);            B = fmaf(Alev0, Bin, B);
                Bin = dpp_bc0<0x112>(B);            B = fmaf(Alev1, Bin, B);
                Bin = dpp_bc0<0x114>(B);            B = fmaf(Alev2, Bin, B);
                Bin = dpp_bc0<0x118>(B);            B = fmaf(Alev3, Bin, B);
                Bin = dpp_mov<0x142, 0xa>(B, 0.0f); B = fmaf(Alev4, Bin, B);
                Bin = dpp_mov<0x143, 0xc>(B, 0.0f); B = fmaf(Alev5, Bin, B);
                Bacc[k] = B;                        // publish later

                const float Tst  = dpp_bc0<0x138>(B);        // excl shift
                const float Tent = fmaf(Aexcl, Tin[k], Tst); // lane entry S

                // ---- flattened per-element exponents
                const float g0 = fmaf(ka0, Tent, fmaf(ivd0, w0, -m0));
                const float g1 = fmaf(ka1, Tent,
                                 fmaf(t10, w0, fmaf(ivd1, w1, -m1)));

                // ---- sigmoid tail: clamp, 2 exp2, ONE shared rcp
                const float e0 = EXP2F(fminf(g0, 30.0f));
                const float e1 = EXP2F(fminf(g1, 30.0f));
                const float q0 = e0 + 1.0f, q1 = e1 + 1.0f;
                const float ip = __builtin_amdgcn_rcpf(q0 * q1);
                // r_i = 1/q_i ; m' = c2 - 2*c2*r = c2*h'
                m0 = fmaf(n2c2, q1 * ip, c2);
                m1 = fmaf(n2c2, q0 * ip, c2);
            }

            // publish composed running total: Tot_w = Bacc + PhiW * Tin
            // (wave w+1 reads it directly as its Tin next tick)
            if (wv < NW - 1 && lane == 63) {
                float4* tp = (float4*)&tot_s[wv][ch * CH];
#pragma unroll
                for (int q = 0; q < CH/4; ++q)
                    tp[q] = make_float4(
                        fmaf(PhiW, Tin[4*q+0], Bacc[4*q+0]),
                        fmaf(PhiW, Tin[4*q+1], Bacc[4*q+1]),
                        fmaf(PhiW, Tin[4*q+2], Bacc[4*q+2]),
                        fmaf(PhiW, Tin[4*q+3], Bacc[4*q+3]));
            }
        }
        __syncthreads();   // one barrier per CHUNK (16 steps)
    }

    // ---- epilogue: h = m/c2; tot = dot(h, C) over this wave's 128 elems
    double acc = 0.0;
    {
        const int base = wv * 128 + lane * 2;
        acc = fma((double)C[base + 0], (double)m0, acc);
        acc = fma((double)C[base + 1], (double)m1, acc);
    }
#pragma unroll
    for (int off = 32; off > 0; off >>= 1)
        acc += __shfl_down(acc, off, 64);
    if (lane == 0) part_s[wv] = acc;
    __syncthreads();
    if (tid < OUT_DIM) {
        double tot = 0.0;
#pragma unroll
        for (int wq = 0; wq < NW; ++wq) tot += part_s[wq];
        tot *= 0.34657359027997264;      // 1/c2 = ln2/2, applied once
        out[b * OUT_DIM + tid] =
            (float)fma(tot, (double)W[tid], (double)bvec[tid]);
    }
}

extern "C" void kernel_launch(void* const* d_in, const int* in_sizes, int n_in,
                              void* d_out, int out_size, void* d_ws, size_t ws_size,
                              hipStream_t stream) {
    const float* x  = (const float*)d_in[0];   // (512, 784, 1)
    const float* C  = (const float*)d_in[1];   // (1, 1024)
    const float* W  = (const float*)d_in[2];   // (1, 10)
    const float* bv = (const float*)d_in[3];   // (10,)
    float* out      = (float*)d_out;           // (512, 10)
    hipLaunchKernelGGL(ssm_hippo_scan, dim3(512), dim3(512), 0, stream,
                       x, C, W, bv, out);
}

// Round 3
// 252.122 us; speedup vs baseline: 1.1240x; 1.1240x over previous
//
#include <hip/hip_runtime.h>
#include <math.h>

// SSM_18597208391915: HiPPO-LegT recurrence, O(N) semiseparable solve.
// Ad = (I-cA)^{-1}(I+cA) = 2M - I  =>  h' = tanh(2*M(h + c*u*P) - h).
// R13: back to R11 structure (NW=4, EPL=4; R12's NW=8/EPL=2 re-tile raised
// total issue 15% -> time +9%: SIMDs are VALU-issue-bound at >=2 waves/SIMD).
// Issue cuts on top of R11:
//   (1) inline-asm v_fmac_f32_dpp scan: all 6 levels are 1 VALU inst each
//       (masked bcast levels were mov0+mov_dpp+fma before). s_nop 1 guards
//       the VALU->DPP 2-wait-state hazard (scalar pipe, free VALU-wise).
//   (2) v_pk_fma_f32/v_pk_mul_f32 for w-pairs, sigmoid-base pairs, B-dot.
//   (3) m' fold: s = n2c2*i once per rcp-pair, then 4 fma.
// Numerics identical to R11 (same composition, clamp 30, quad shared rcp).

#define SEQ     784
#define OUT_DIM 10
#define NW      4
#define CH      16            // steps per chunk
#define NCH     (SEQ/CH)      // 49
#define EPL     4             // elems/lane: NW*64*EPL = 1024 = HIDDEN

typedef float v2f __attribute__((ext_vector_type(2)));

#if __has_builtin(__builtin_elementwise_fma)
__device__ __forceinline__ v2f fma2(v2f a, v2f b, v2f c) {
    return __builtin_elementwise_fma(a, b, c);
}
#else
__device__ __forceinline__ v2f fma2(v2f a, v2f b, v2f c) {
    v2f r; r.x = fmaf(a.x, b.x, c.x); r.y = fmaf(a.y, b.y, c.y); return r;
}
#endif

#if __has_builtin(__builtin_amdgcn_exp2f)
#define EXP2F(x) __builtin_amdgcn_exp2f(x)
#else
#define EXP2F(x) __expf(0.69314718055994531f * (x))
#endif

// DPP move with explicit old: masked/invalid lanes get `old`. (setup only)
template<int CTRL, int ROW_MASK>
__device__ __forceinline__ float dpp_mov(float src, float old) {
    return __int_as_float(__builtin_amdgcn_update_dpp(
        __float_as_int(old), __float_as_int(src), CTRL, ROW_MASK, 0xf, false));
}
// DPP move, bound_ctrl: invalid lanes read 0.
template<int CTRL>
__device__ __forceinline__ float dpp_bc0(float src) {
    return __int_as_float(__builtin_amdgcn_update_dpp(
        0, __float_as_int(src), CTRL, 0xf, 0xf, true));
}
// ctrls: row_shr:N = 0x110|N, row_bcast15 = 0x142, row_bcast31 = 0x143,
//        wave_shr:1 = 0x138

__global__ __launch_bounds__(256, 2)
void ssm_hippo_scan(const float* __restrict__ x,     // (512, 784)
                    const float* __restrict__ C,     // (1024)
                    const float* __restrict__ W,     // (10)
                    const float* __restrict__ bvec,  // (10)
                    float* __restrict__ out)         // (512, 10)
{
    const int b    = blockIdx.x;
    const int tid  = threadIdx.x;
    const int wv   = tid >> 6;       // wave w owns elems [w*256, w*256+256)
    const int lane = tid & 63;

    __shared__ __align__(16) float u_s[SEQ];
    __shared__ __align__(16) float totB_s[NW-1][SEQ]; // inclusive-B streams
    __shared__ double part_s[NW];

    for (int t = tid; t < SEQ; t += 256) u_s[t] = x[b * SEQ + t];

    const double hdt  = 0.5 / (double)SEQ;            // c = dt/2
    const double L2E2 = 2.0 * 1.4426950408889634;     // 2*log2(e)

    // ---- per-element constants (n = wv*256 + lane*EPL + i), fp64-derived.
    v2f upc01, upc23, ivd01, ivd23, cB01, cB23;
    float ka0, ka1, ka2, ka3;
    float t10, t20, t21, t30, t31, t32;
    float Alev0, Alev1, Alev2, Alev3, Alev4, Alev5, Aexcl;
    float c2, n2c2;
    {
        double p[EPL], d[EPL], a[EPL], pdin[EPL], hp[EPL];
#pragma unroll
        for (int i = 0; i < EPL; ++i) {
            const int n = wv * 256 + lane * EPL + i;
            p[i]    = sqrt(1.0 + 2.0 * (double)n);
            d[i]    = 1.0 + hdt * (double)(n + 1);
            a[i]    = 1.0 - hdt * p[i] * p[i] / d[i];
            pdin[i] = p[i] / d[i];
            hp[i]   = 2.0 * hdt * p[i] / d[i];
        }
        upc01 = (v2f){(float)(L2E2 * hdt * p[0]), (float)(L2E2 * hdt * p[1])};
        upc23 = (v2f){(float)(L2E2 * hdt * p[2]), (float)(L2E2 * hdt * p[3])};
        ivd01 = (v2f){(float)(2.0 / d[0]), (float)(2.0 / d[1])};
        ivd23 = (v2f){(float)(2.0 / d[2]), (float)(2.0 / d[3])};
        ka0 = (float)(-hp[0]);
        ka1 = (float)(-hp[1] * a[0]);
        ka2 = (float)(-hp[2] * a[0]*a[1]);
        ka3 = (float)(-hp[3] * a[0]*a[1]*a[2]);
        cB01 = (v2f){(float)(a[1]*a[2]*a[3] * pdin[0]),
                     (float)(a[2]*a[3] * pdin[1])};
        cB23 = (v2f){(float)(a[3] * pdin[2]), (float)(pdin[3])};
        t10 = (float)(-hp[1] * pdin[0]);
        t20 = (float)(-hp[2] * a[1] * pdin[0]);
        t21 = (float)(-hp[2] * pdin[1]);
        t30 = (float)(-hp[3] * a[2] * a[1] * pdin[0]);
        t31 = (float)(-hp[3] * a[2] * pdin[1]);
        t32 = (float)(-hp[3] * pdin[2]);

        float A = (float)(a[0]*a[1]*a[2]*a[3]);   // per-lane decay
        Alev0 = A; A *= dpp_mov<0x111, 0xf>(A, 1.0f);
        Alev1 = A; A *= dpp_mov<0x112, 0xf>(A, 1.0f);
        Alev2 = A; A *= dpp_mov<0x114, 0xf>(A, 1.0f);
        Alev3 = A; A *= dpp_mov<0x118, 0xf>(A, 1.0f);
        Alev4 = A; A *= dpp_mov<0x142, 0xa>(A, 1.0f);
        Alev5 = A; A *= dpp_mov<0x143, 0xc>(A, 1.0f);
        Aexcl = dpp_mov<0x138, 0xf>(A, 1.0f);     // lane0 -> 1 (excl prod)

        c2   = (float)L2E2;
        n2c2 = (float)(-2.0 * L2E2);
    }

    // inter-wave composition coefficients (closed-form Phi products, fp64)
    float cF1 = 0.0f, cF2 = 0.0f, cF12 = 0.0f;
    {
        double n1 = 1.0, d1 = 1.0, n2 = 1.0, d2 = 1.0;
        for (int n = 256; n < 512; ++n) {
            n1 *= 1.0 - hdt * (double)n; d1 *= 1.0 + hdt * (double)(n + 1);
        }
        for (int n = 512; n < 768; ++n) {
            n2 *= 1.0 - hdt * (double)n; d2 *= 1.0 + hdt * (double)(n + 1);
        }
        const double Phi1 = n1 / d1, Phi2 = n2 / d2;
        cF1 = (float)Phi1; cF2 = (float)Phi2; cF12 = (float)(Phi1 * Phi2);
    }

    __syncthreads();                         // u_s ready

    // ---- state: m = c2 * h   (h = 0 -> m = 0), stored as pairs
    v2f m01 = (v2f){0.0f, 0.0f}, m23 = (v2f){0.0f, 0.0f};

#pragma unroll 1
    for (int tick = 0; tick < NCH + NW - 1; ++tick) {
        const int ch = tick - wv;            // this wave's chunk index
        if (0 <= ch && ch < NCH) {
            // ---- bulk register loads: u's and incoming-B composition
            float4 u4[CH/4];
            float  Tin[CH];
            {
                const float4* up = (const float4*)&u_s[ch * CH];
#pragma unroll
                for (int q = 0; q < CH/4; ++q) u4[q] = up[q];
            }
            if (wv == 0) {
#pragma unroll
                for (int k = 0; k < CH; ++k) Tin[k] = 0.0f;
            } else if (wv == 1) {
                const float4* b0 = (const float4*)&totB_s[0][ch * CH];
#pragma unroll
                for (int q = 0; q < CH/4; ++q) {
                    const float4 v0 = b0[q];
                    Tin[4*q+0] = v0.x; Tin[4*q+1] = v0.y;
                    Tin[4*q+2] = v0.z; Tin[4*q+3] = v0.w;
                }
            } else if (wv == 2) {
                const float4* b0 = (const float4*)&totB_s[0][ch * CH];
                const float4* b1 = (const float4*)&totB_s[1][ch * CH];
#pragma unroll
                for (int q = 0; q < CH/4; ++q) {
                    const float4 v0 = b0[q], v1 = b1[q];
                    Tin[4*q+0] = fmaf(cF1, v0.x, v1.x);
                    Tin[4*q+1] = fmaf(cF1, v0.y, v1.y);
                    Tin[4*q+2] = fmaf(cF1, v0.z, v1.z);
                    Tin[4*q+3] = fmaf(cF1, v0.w, v1.w);
                }
            } else {
                const float4* b0 = (const float4*)&totB_s[0][ch * CH];
                const float4* b1 = (const float4*)&totB_s[1][ch * CH];
                const float4* b2 = (const float4*)&totB_s[2][ch * CH];
#pragma unroll
                for (int q = 0; q < CH/4; ++q) {
                    const float4 v0 = b0[q], v1 = b1[q], v2 = b2[q];
                    Tin[4*q+0] = fmaf(cF12, v0.x, fmaf(cF2, v1.x, v2.x));
                    Tin[4*q+1] = fmaf(cF12, v0.y, fmaf(cF2, v1.y, v2.y));
                    Tin[4*q+2] = fmaf(cF12, v0.z, fmaf(cF2, v1.z, v2.z));
                    Tin[4*q+3] = fmaf(cF12, v0.w, fmaf(cF2, v1.w, v2.w));
                }
            }
            float Bacc[CH];

#pragma unroll
            for (int k = 0; k < CH; ++k) {
                const float u = ((const float*)&u4[k>>2])[k&3];
                const v2f  uu = (v2f){u, u};

                // ---- head: w_i = upc_i*u + m_i   (packed)
                const v2f w01 = fma2(upc01, uu, m01);
                const v2f w23 = fma2(upc23, uu, m23);

                // ---- lane-inclusive affine-B (packed dot + h-add)
                const v2f bt = fma2(cB23, w23, cB01 * w01);
                float B = bt.x + bt.y;

                // ---- cross-lane affine scan: 6x v_fmac_f32_dpp.
                // s_nop 1 = 2 wait states for the VALU-write -> DPP-read
                // hazard (incl. entry: B written by pk-add above; exit:
                // following mov_dpp reads B). s_nop issues on scalar pipe.
                asm volatile(
                    "s_nop 1\n\t"
                    "v_fmac_f32_dpp %0, %0, %1 row_shr:1 row_mask:0xf bank_mask:0xf bound_ctrl:0\n\t"
                    "s_nop 1\n\t"
                    "v_fmac_f32_dpp %0, %0, %2 row_shr:2 row_mask:0xf bank_mask:0xf bound_ctrl:0\n\t"
                    "s_nop 1\n\t"
                    "v_fmac_f32_dpp %0, %0, %3 row_shr:4 row_mask:0xf bank_mask:0xf bound_ctrl:0\n\t"
                    "s_nop 1\n\t"
                    "v_fmac_f32_dpp %0, %0, %4 row_shr:8 row_mask:0xf bank_mask:0xf bound_ctrl:0\n\t"
                    "s_nop 1\n\t"
                    "v_fmac_f32_dpp %0, %0, %5 row_bcast:15 row_mask:0xa bank_mask:0xf\n\t"
                    "s_nop 1\n\t"
                    "v_fmac_f32_dpp %0, %0, %6 row_bcast:31 row_mask:0xc bank_mask:0xf\n\t"
                    "s_nop 1\n\t"
                    : "+v"(B)
                    : "v"(Alev0), "v"(Alev1), "v"(Alev2), "v"(Alev3),
                      "v"(Alev4), "v"(Alev5));
                Bacc[k] = B;                        // publish later

                const float Tst  = dpp_bc0<0x138>(B);        // excl shift
                const float Tent = fmaf(Aexcl, Tin[k], Tst); // lane entry S

                // ---- flattened per-element g (exponent of sigmoid)
                const v2f b01 = fma2(ivd01, w01, -m01);
                const v2f b23 = fma2(ivd23, w23, -m23);
                const float g0 = fmaf(ka0, Tent, b01.x);
                const float g1 = fmaf(ka1, Tent, fmaf(t10, w01.x, b01.y));
                const float g2 = fmaf(ka2, Tent,
                                 fmaf(t20, w01.x, fmaf(t21, w01.y, b23.x)));
                const float g3 = fmaf(ka3, Tent,
                                 fmaf(t30, w01.x,
                                 fmaf(t31, w01.y, fmaf(t32, w23.x, b23.y))));

                // ---- sigmoid tail: clamp, 4 exp2, ONE shared rcp, s-fold
                const float e0 = EXP2F(fminf(g0, 30.0f));
                const float e1 = EXP2F(fminf(g1, 30.0f));
                const float e2 = EXP2F(fminf(g2, 30.0f));
                const float e3 = EXP2F(fminf(g3, 30.0f));
                const float q0 = e0 + 1.0f, q1 = e1 + 1.0f;
                const float q2 = e2 + 1.0f, q3 = e3 + 1.0f;
                const float p01 = q0 * q1, p23 = q2 * q3;
                const float ip  = __builtin_amdgcn_rcpf(p01 * p23);
                const float s01 = n2c2 * (p23 * ip);   // n2c2 / (q0*q1)
                const float s23 = n2c2 * (p01 * ip);   // n2c2 / (q2*q3)
                // m_i' = c2 + n2c2/q_i
                m01.x = fmaf(s01, q1, c2);
                m01.y = fmaf(s01, q0, c2);
                m23.x = fmaf(s23, q3, c2);
                m23.y = fmaf(s23, q2, c2);
            }

            // publish this wave's chunk B-totals (lane 63 holds them)
            if (wv < NW - 1 && lane == 63) {
                float4* tp = (float4*)&totB_s[wv][ch * CH];
#pragma unroll
                for (int q = 0; q < CH/4; ++q)
                    tp[q] = make_float4(Bacc[4*q], Bacc[4*q+1],
                                        Bacc[4*q+2], Bacc[4*q+3]);
            }
        }
        __syncthreads();   // one barrier per CHUNK (16 steps)
    }

    // ---- epilogue: h = m/c2; tot = dot(h, C) over this wave's 256 elems
    double acc = 0.0;
    {
        const int base = wv * 256 + lane * EPL;
        acc = fma((double)C[base + 0], (double)m01.x, acc);
        acc = fma((double)C[base + 1], (double)m01.y, acc);
        acc = fma((double)C[base + 2], (double)m23.x, acc);
        acc = fma((double)C[base + 3], (double)m23.y, acc);
    }
#pragma unroll
    for (int off = 32; off > 0; off >>= 1)
        acc += __shfl_down(acc, off, 64);
    if (lane == 0) part_s[wv] = acc;
    __syncthreads();
    if (tid < OUT_DIM) {
        // scale by 1/c2 = ln2/2 once, in fp64
        const double tot = (part_s[0] + part_s[1] + part_s[2] + part_s[3])
                         * 0.34657359027997264;
        out[b * OUT_DIM + tid] =
            (float)fma(tot, (double)W[tid], (double)bvec[tid]);
    }
}

extern "C" void kernel_launch(void* const* d_in, const int* in_sizes, int n_in,
                              void* d_out, int out_size, void* d_ws, size_t ws_size,
                              hipStream_t stream) {
    const float* x  = (const float*)d_in[0];   // (512, 784, 1)
    const float* C  = (const float*)d_in[1];   // (1, 1024)
    const float* W  = (const float*)d_in[2];   // (1, 10)
    const float* bv = (const float*)d_in[3];   // (10,)
    float* out      = (float*)d_out;           // (512, 10)
    hipLaunchKernelGGL(ssm_hippo_scan, dim3(512), dim3(256), 0, stream,
                       x, C, W, bv, out);
}

// Round 4
// 241.260 us; speedup vs baseline: 1.1746x; 1.0450x over previous
//
#include <hip/hip_runtime.h>
#include <math.h>

// SSM_18597208391915: HiPPO-LegT recurrence, O(N) semiseparable solve.
// Ad = (I-cA)^{-1}(I+cA) = 2M - I  =>  h' = tanh(2*M(h + c*u*P) - h).
// R14: dual-batch lane-split. R11-R13 showed wall ~ total VALU issue
// (DPP~8cy, trans~16cy, issue-bound at 2 waves/SIMD). Every step inst is
// per-lane, so: 2 batch elems per block, lanes 0-31 = batch A, 32-63 =
// batch B. The 64-lane scan becomes two 32-lane scans, NATIVE to DPP
// (row_shr:1/2/4/8 + row_bcast15 row_mask:0xa never cross lane 32).
// Same per-wave-step issue as R13 but TWO batch-steps completed -> per-
// batch issue halves. NW=8 waves x 32 lanes x EPL=4 = 1024 hidden/batch;
// 256 blocks x 512 thr = 2048 waves = 2/SIMD (unchanged occupancy).
//   - exclusive shift per half: row_shr:1 (bc0) + bcast15 fix at lh==16
//     (lanes 16,48) via cndmask.
//   - composed-stream publish (R12-verified): wave w publishes
//     Tot = Bacc + PhiW*Tin from lanes 31 AND 63; reader reads ONE stream.
//   - g-triangle fmas ride inside the scan asm as DPP-hazard fillers.
//   - ticks: NCH+NW-1 = 56 (vs 52, +8% - paid for by 2x amortization).

#define SEQ     784
#define OUT_DIM 10
#define NW      8
#define CH      16            // steps per chunk
#define NCH     (SEQ/CH)      // 49
#define EPL     4             // elems per lane per batch: 8*32*4 = 1024

#if __has_builtin(__builtin_amdgcn_exp2f)
#define EXP2F(x) __builtin_amdgcn_exp2f(x)
#else
#define EXP2F(x) __expf(0.69314718055994531f * (x))
#endif

// DPP move with explicit old: masked/invalid lanes get `old`. (setup only)
template<int CTRL, int ROW_MASK>
__device__ __forceinline__ float dpp_mov(float src, float old) {
    return __int_as_float(__builtin_amdgcn_update_dpp(
        __float_as_int(old), __float_as_int(src), CTRL, ROW_MASK, 0xf, false));
}
// ctrls: row_shr:N = 0x110|N, row_bcast15 = 0x142

__global__ __launch_bounds__(512, 2)
void ssm_hippo_scan(const float* __restrict__ x,     // (512, 784)
                    const float* __restrict__ C,     // (1024)
                    const float* __restrict__ W,     // (10)
                    const float* __restrict__ bvec,  // (10)
                    float* __restrict__ out)         // (512, 10)
{
    const int b0   = blockIdx.x * 2;   // this block's two batch elems
    const int tid  = threadIdx.x;
    const int wv   = tid >> 6;         // wave: hidden slice [wv*128, +128)
    const int lane = tid & 63;
    const int lh   = lane & 31;        // lane within half
    const int h    = lane >> 5;        // 0 = batch b0, 1 = batch b0+1

    __shared__ __align__(16) float u_s[2][SEQ];
    __shared__ __align__(16) float tot_s[NW-1][2][SEQ]; // composed B-streams
    __shared__ double part_s[NW][2];

    for (int t = tid; t < SEQ; t += 512) {
        u_s[0][t] = x[(b0 + 0) * SEQ + t];
        u_s[1][t] = x[(b0 + 1) * SEQ + t];
    }

    const double hdt  = 0.5 / (double)SEQ;            // c = dt/2
    const double L2E2 = 2.0 * 1.4426950408889634;     // 2*log2(e)

    // ---- per-element constants (n = wv*128 + lh*4 + i) - SAME for both
    // halves (depend on lane&31 only). fp64-derived.
    // Exponent-space recurrence (w = m + upc*u, m = c2*h):
    //   S_{n+1} = alpha_n S_n + pdin_n w_n ; g_n = ivd_n w_n - m_n - hp_n S_n
    float upc0, upc1, upc2, upc3, ivd0, ivd1, ivd2, ivd3;
    float ka0, ka1, ka2, ka3, cB0, cB1, cB2, cB3;
    float t10, t20, t21, t30, t31, t32;
    float Alev0, Alev1, Alev2, Alev3, Alev4, Aexcl;
    float PhiW, c2, n2c2;
    {
        double p[EPL], d[EPL], a[EPL], pdin[EPL], hp[EPL];
#pragma unroll
        for (int i = 0; i < EPL; ++i) {
            const int n = wv * 128 + lh * EPL + i;
            p[i]    = sqrt(1.0 + 2.0 * (double)n);
            d[i]    = 1.0 + hdt * (double)(n + 1);
            a[i]    = 1.0 - hdt * p[i] * p[i] / d[i];
            pdin[i] = p[i] / d[i];
            hp[i]   = 2.0 * hdt * p[i] / d[i];
        }
        upc0 = (float)(L2E2 * hdt * p[0]); upc1 = (float)(L2E2 * hdt * p[1]);
        upc2 = (float)(L2E2 * hdt * p[2]); upc3 = (float)(L2E2 * hdt * p[3]);
        ivd0 = (float)(2.0 / d[0]); ivd1 = (float)(2.0 / d[1]);
        ivd2 = (float)(2.0 / d[2]); ivd3 = (float)(2.0 / d[3]);
        ka0 = (float)(-hp[0]);
        ka1 = (float)(-hp[1] * a[0]);
        ka2 = (float)(-hp[2] * a[0]*a[1]);
        ka3 = (float)(-hp[3] * a[0]*a[1]*a[2]);
        cB0 = (float)(a[1]*a[2]*a[3] * pdin[0]);
        cB1 = (float)(a[2]*a[3] * pdin[1]);
        cB2 = (float)(a[3] * pdin[2]);
        cB3 = (float)(pdin[3]);
        t10 = (float)(-hp[1] * pdin[0]);
        t20 = (float)(-hp[2] * a[1] * pdin[0]);
        t21 = (float)(-hp[2] * pdin[1]);
        t30 = (float)(-hp[3] * a[2] * a[1] * pdin[0]);
        t31 = (float)(-hp[3] * a[2] * pdin[1]);
        t32 = (float)(-hp[3] * pdin[2]);

        // 32-lane scan level constants (5 levels; never cross lane 32)
        float A = (float)(a[0]*a[1]*a[2]*a[3]);   // per-lane decay
        Alev0 = A; A *= dpp_mov<0x111, 0xf>(A, 1.0f);  // row_shr:1
        Alev1 = A; A *= dpp_mov<0x112, 0xf>(A, 1.0f);  // row_shr:2
        Alev2 = A; A *= dpp_mov<0x114, 0xf>(A, 1.0f);  // row_shr:4
        Alev3 = A; A *= dpp_mov<0x118, 0xf>(A, 1.0f);  // row_shr:8
        Alev4 = A; A *= dpp_mov<0x142, 0xa>(A, 1.0f);  // bcast15 rows 1,3
        // A = 32-lane inclusive alpha-product per half
        const float Ae_raw = dpp_mov<0x111, 0xf>(A, 1.0f); // shift, old=1
        const float Ae_fix = dpp_mov<0x142, 0xa>(A, 1.0f); // lane15/47 val
        Aexcl = (lh == 16) ? Ae_fix : Ae_raw;  // exclusive alpha-product

        // own wave's total decay Phi over its 128 elems (closed form)
        double np = 1.0, dp = 1.0;
        for (int n = wv * 128; n < wv * 128 + 128; ++n) {
            np *= 1.0 - hdt * (double)n;
            dp *= 1.0 + hdt * (double)(n + 1);
        }
        PhiW = (float)(np / dp);

        c2   = (float)L2E2;
        n2c2 = (float)(-2.0 * L2E2);
    }

    const bool fixlane = (lh == 16);   // lanes 16, 48: row-boundary fix

    __syncthreads();                   // u_s ready

    // ---- state: m = c2 * h   (h = 0 -> m = 0)
    float m0 = 0.0f, m1 = 0.0f, m2 = 0.0f, m3 = 0.0f;
    float Bf = 0.0f;                   // bcast15 fix reg (rows 0,2 unused)

#pragma unroll 1
    for (int tick = 0; tick < NCH + NW - 1; ++tick) {
        const int ch = tick - wv;      // this wave's chunk index
        if (0 <= ch && ch < NCH) {
            // ---- bulk register loads: u's and the one incoming stream
            float4 u4[CH/4];
            float  Tin[CH];
            {
                const float4* up = (const float4*)&u_s[h][ch * CH];
#pragma unroll
                for (int q = 0; q < CH/4; ++q) u4[q] = up[q];
            }
            if (wv == 0) {
#pragma unroll
                for (int k = 0; k < CH; ++k) Tin[k] = 0.0f;
            } else {
                const float4* bp = (const float4*)&tot_s[wv - 1][h][ch * CH];
#pragma unroll
                for (int q = 0; q < CH/4; ++q) {
                    const float4 v0 = bp[q];
                    Tin[4*q+0] = v0.x; Tin[4*q+1] = v0.y;
                    Tin[4*q+2] = v0.z; Tin[4*q+3] = v0.w;
                }
            }
            float Bacc[CH];

#pragma unroll
            for (int k = 0; k < CH; ++k) {
                const float u = ((const float*)&u4[k>>2])[k&3];

                // ---- head: w_i = upc_i*u + m_i
                const float w0 = fmaf(upc0, u, m0);
                const float w1 = fmaf(upc1, u, m1);
                const float w2 = fmaf(upc2, u, m2);
                const float w3 = fmaf(upc3, u, m3);

                // ---- sigmoid bases (ready early; b1..b3 feed asm fillers)
                const float bb0 = fmaf(ivd0, w0, -m0);
                const float bb1 = fmaf(ivd1, w1, -m1);
                const float bb2 = fmaf(ivd2, w2, -m2);
                const float bb3 = fmaf(ivd3, w3, -m3);

                // ---- lane-inclusive affine-B (tree, short chain)
                float B = fmaf(cB0, w0, cB1 * w1) + fmaf(cB2, w2, cB3 * w3);

                // ---- 32-lane affine scan (5 DPP levels) + exclusive shift,
                // with the g-triangle fmas as DPP-hazard fillers.
                float Tr, g1t, g2t, g3t;
                asm volatile(
                    "s_nop 1\n\t"
                    "v_fmac_f32_dpp %[B], %[B], %[A0] row_shr:1 row_mask:0xf bank_mask:0xf bound_ctrl:0\n\t"
                    "v_fma_f32 %[g1], %[c10], %[w0], %[b1]\n\t"
                    "v_fmac_f32_dpp %[B], %[B], %[A1] row_shr:2 row_mask:0xf bank_mask:0xf bound_ctrl:0\n\t"
                    "v_fma_f32 %[g2], %[c21], %[w1], %[b2]\n\t"
                    "v_fmac_f32_dpp %[B], %[B], %[A2] row_shr:4 row_mask:0xf bank_mask:0xf bound_ctrl:0\n\t"
                    "v_fma_f32 %[g2], %[c20], %[w0], %[g2]\n\t"
                    "v_fmac_f32_dpp %[B], %[B], %[A3] row_shr:8 row_mask:0xf bank_mask:0xf bound_ctrl:0\n\t"
                    "v_fma_f32 %[g3], %[c32], %[w2], %[b3]\n\t"
                    "v_fmac_f32_dpp %[B], %[B], %[A4] row_bcast:15 row_mask:0xa bank_mask:0xf\n\t"
                    "v_fma_f32 %[g3], %[c31], %[w1], %[g3]\n\t"
                    "v_mov_b32_dpp %[Tr], %[B] row_shr:1 row_mask:0xf bank_mask:0xf bound_ctrl:0\n\t"
                    "v_fma_f32 %[g3], %[c30], %[w0], %[g3]\n\t"
                    "v_mov_b32_dpp %[Bf], %[B] row_bcast:15 row_mask:0xa bank_mask:0xf\n\t"
                    : [B]"+v"(B), [Tr]"=&v"(Tr), [Bf]"+v"(Bf),
                      [g1]"=&v"(g1t), [g2]"=&v"(g2t), [g3]"=&v"(g3t)
                    : [A0]"v"(Alev0), [A1]"v"(Alev1), [A2]"v"(Alev2),
                      [A3]"v"(Alev3), [A4]"v"(Alev4),
                      [c10]"v"(t10), [c20]"v"(t20), [c21]"v"(t21),
                      [c30]"v"(t30), [c31]"v"(t31), [c32]"v"(t32),
                      [w0]"v"(w0), [w1]"v"(w1), [w2]"v"(w2),
                      [b1]"v"(bb1), [b2]"v"(bb2), [b3]"v"(bb3));
                Bacc[k] = B;                        // publish later

                // exclusive prefix: lanes 0,32 -> 0; 16,48 -> lane15/47's B
                const float Tst  = fixlane ? Bf : Tr;
                const float Tent = fmaf(Aexcl, Tin[k], Tst); // lane entry S

                // ---- flattened per-element exponents
                const float g0 = fmaf(ka0, Tent, bb0);
                const float g1 = fmaf(ka1, Tent, g1t);
                const float g2 = fmaf(ka2, Tent, g2t);
                const float g3 = fmaf(ka3, Tent, g3t);

                // ---- sigmoid tail: clamp, 4 exp2, ONE shared rcp
                const float e0 = EXP2F(fminf(g0, 30.0f));
                const float e1 = EXP2F(fminf(g1, 30.0f));
                const float e2 = EXP2F(fminf(g2, 30.0f));
                const float e3 = EXP2F(fminf(g3, 30.0f));
                const float q0 = e0 + 1.0f, q1 = e1 + 1.0f;
                const float q2 = e2 + 1.0f, q3 = e3 + 1.0f;
                const float p01 = q0 * q1, p23 = q2 * q3;
                const float ip  = __builtin_amdgcn_rcpf(p01 * p23);
                const float tt  = n2c2 * ip;
                const float s01 = tt * p23;            // n2c2 / (q0*q1)
                const float s23 = tt * p01;            // n2c2 / (q2*q3)
                // m_i' = c2 + n2c2/q_i
                m0 = fmaf(s01, q1, c2);
                m1 = fmaf(s01, q0, c2);
                m2 = fmaf(s23, q3, c2);
                m3 = fmaf(s23, q2, c2);
            }

            // publish composed running totals from BOTH half-ends:
            // lane 31 (batch h=0) and lane 63 (batch h=1)
            if (wv < NW - 1 && lh == 31) {
                float4* tp = (float4*)&tot_s[wv][h][ch * CH];
#pragma unroll
                for (int q = 0; q < CH/4; ++q)
                    tp[q] = make_float4(
                        fmaf(PhiW, Tin[4*q+0], Bacc[4*q+0]),
                        fmaf(PhiW, Tin[4*q+1], Bacc[4*q+1]),
                        fmaf(PhiW, Tin[4*q+2], Bacc[4*q+2]),
                        fmaf(PhiW, Tin[4*q+3], Bacc[4*q+3]));
            }
        }
        __syncthreads();   // one barrier per CHUNK (16 steps)
    }

    // ---- epilogue: h = m/c2; per-half dot(h, C) over 128 elems
    double acc = 0.0;
    {
        const int base = wv * 128 + lh * EPL;
        acc = fma((double)C[base + 0], (double)m0, acc);
        acc = fma((double)C[base + 1], (double)m1, acc);
        acc = fma((double)C[base + 2], (double)m2, acc);
        acc = fma((double)C[base + 3], (double)m3, acc);
    }
#pragma unroll
    for (int off = 16; off > 0; off >>= 1)
        acc += __shfl_down(acc, off, 32);     // within 32-lane halves
    if (lh == 0) part_s[wv][h] = acc;
    __syncthreads();
    if (tid < 2 * OUT_DIM) {
        const int q = tid / OUT_DIM, j = tid - q * OUT_DIM;
        double tot = 0.0;
#pragma unroll
        for (int wq = 0; wq < NW; ++wq) tot += part_s[wq][q];
        tot *= 0.34657359027997264;           // 1/c2 = ln2/2, applied once
        out[(b0 + q) * OUT_DIM + j] =
            (float)fma(tot, (double)W[j], (double)bvec[j]);
    }
}

extern "C" void kernel_launch(void* const* d_in, const int* in_sizes, int n_in,
                              void* d_out, int out_size, void* d_ws, size_t ws_size,
                              hipStream_t stream) {
    const float* x  = (const float*)d_in[0];   // (512, 784, 1)
    const float* C  = (const float*)d_in[1];   // (1, 1024)
    const float* W  = (const float*)d_in[2];   // (1, 10)
    const float* bv = (const float*)d_in[3];   // (10,)
    float* out      = (float*)d_out;           // (512, 10)
    hipLaunchKernelGGL(ssm_hippo_scan, dim3(256), dim3(512), 0, stream,
                       x, C, W, bv, out);
}

// Round 5
// 239.272 us; speedup vs baseline: 1.1843x; 1.0083x over previous
//
#include <hip/hip_runtime.h>
#include <math.h>

// SSM_18597208391915: HiPPO-LegT recurrence, O(N) semiseparable solve.
// Ad = (I-cA)^{-1}(I+cA) = 2M - I  =>  h' = tanh(2*M(h + c*u*P) - h).
// R15: VOP3P re-pack of the R14 dual-batch body. R14 post-mortem: the
// lane-split didn't cut total issue (per-wave work halved too); body was
// all-scalar. This round packs every pairwise op into v_pk_* (one inst
// per pair): head, bases, B-dot, g-triangle, g, q-adds, s-fold, m'.
// Scan stays 5x v_fmac_f32_dpp + 2 mov_dpp, now as chained single-DPP
// asm blocks (order forced by B dataflow) with packed triangle ops
// between them as hazard fillers; each block self-guards with s_nop 1.
// Structure from R14 (verified): 2 batches/block in lane halves, NW=8,
// EPL=4, composed-stream publish, 16-step register inner loop, one
// barrier per chunk.

#define SEQ     784
#define OUT_DIM 10
#define NW      8
#define CH      16            // steps per chunk
#define NCH     (SEQ/CH)      // 49
#define EPL     4             // elems per lane per batch: 8*32*4 = 1024

typedef float v2f __attribute__((ext_vector_type(2)));

#if __has_builtin(__builtin_elementwise_fma)
__device__ __forceinline__ v2f fma2(v2f a, v2f b, v2f c) {
    return __builtin_elementwise_fma(a, b, c);
}
#else
__device__ __forceinline__ v2f fma2(v2f a, v2f b, v2f c) {
    v2f r; r.x = fmaf(a.x, b.x, c.x); r.y = fmaf(a.y, b.y, c.y); return r;
}
#endif

#if __has_builtin(__builtin_amdgcn_exp2f)
#define EXP2F(x) __builtin_amdgcn_exp2f(x)
#else
#define EXP2F(x) __expf(0.69314718055994531f * (x))
#endif

// DPP move with explicit old: masked/invalid lanes get `old`. (setup only)
template<int CTRL, int ROW_MASK>
__device__ __forceinline__ float dpp_mov(float src, float old) {
    return __int_as_float(__builtin_amdgcn_update_dpp(
        __float_as_int(old), __float_as_int(src), CTRL, ROW_MASK, 0xf, false));
}
// ctrls: row_shr:N = 0x110|N, row_bcast15 = 0x142

__global__ __launch_bounds__(512, 2)
void ssm_hippo_scan(const float* __restrict__ x,     // (512, 784)
                    const float* __restrict__ C,     // (1024)
                    const float* __restrict__ W,     // (10)
                    const float* __restrict__ bvec,  // (10)
                    float* __restrict__ out)         // (512, 10)
{
    const int b0   = blockIdx.x * 2;   // this block's two batch elems
    const int tid  = threadIdx.x;
    const int wv   = tid >> 6;         // wave: hidden slice [wv*128, +128)
    const int lane = tid & 63;
    const int lh   = lane & 31;        // lane within half
    const int h    = lane >> 5;        // 0 = batch b0, 1 = batch b0+1

    __shared__ __align__(16) float u_s[2][SEQ];
    __shared__ __align__(16) float tot_s[NW-1][2][SEQ]; // composed B-streams
    __shared__ double part_s[NW][2];

    for (int t = tid; t < SEQ; t += 512) {
        u_s[0][t] = x[(b0 + 0) * SEQ + t];
        u_s[1][t] = x[(b0 + 1) * SEQ + t];
    }

    const double hdt  = 0.5 / (double)SEQ;            // c = dt/2
    const double L2E2 = 2.0 * 1.4426950408889634;     // 2*log2(e)

    // ---- per-element constants (n = wv*128 + lh*4 + i) - SAME for both
    // halves (depend on lane&31 only). fp64-derived.
    // Exponent-space recurrence (w = m + upc*u, m = c2*h):
    //   S_{n+1} = alpha_n S_n + pdin_n w_n ; g_n = ivd_n w_n - m_n - hp_n S_n
    v2f upc01, upc23, ivd01, ivd23, cB01, cB23;
    v2f ka01, ka23, c20_30, c21_31;
    float t10, t32;
    float Alev0, Alev1, Alev2, Alev3, Alev4, Aexcl;
    float PhiW, c2, n2c2;
    {
        double p[EPL], d[EPL], a[EPL], pdin[EPL], hp[EPL];
#pragma unroll
        for (int i = 0; i < EPL; ++i) {
            const int n = wv * 128 + lh * EPL + i;
            p[i]    = sqrt(1.0 + 2.0 * (double)n);
            d[i]    = 1.0 + hdt * (double)(n + 1);
            a[i]    = 1.0 - hdt * p[i] * p[i] / d[i];
            pdin[i] = p[i] / d[i];
            hp[i]   = 2.0 * hdt * p[i] / d[i];
        }
        upc01 = (v2f){(float)(L2E2 * hdt * p[0]), (float)(L2E2 * hdt * p[1])};
        upc23 = (v2f){(float)(L2E2 * hdt * p[2]), (float)(L2E2 * hdt * p[3])};
        ivd01 = (v2f){(float)(2.0 / d[0]), (float)(2.0 / d[1])};
        ivd23 = (v2f){(float)(2.0 / d[2]), (float)(2.0 / d[3])};
        ka01  = (v2f){(float)(-hp[0]), (float)(-hp[1] * a[0])};
        ka23  = (v2f){(float)(-hp[2] * a[0]*a[1]),
                      (float)(-hp[3] * a[0]*a[1]*a[2])};
        cB01  = (v2f){(float)(a[1]*a[2]*a[3] * pdin[0]),
                      (float)(a[2]*a[3] * pdin[1])};
        cB23  = (v2f){(float)(a[3] * pdin[2]), (float)(pdin[3])};
        t10   = (float)(-hp[1] * pdin[0]);
        c20_30= (v2f){(float)(-hp[2] * a[1] * pdin[0]),
                      (float)(-hp[3] * a[2] * a[1] * pdin[0])};
        c21_31= (v2f){(float)(-hp[2] * pdin[1]),
                      (float)(-hp[3] * a[2] * pdin[1])};
        t32   = (float)(-hp[3] * pdin[2]);

        // 32-lane scan level constants (5 levels; never cross lane 32)
        float A = (float)(a[0]*a[1]*a[2]*a[3]);   // per-lane decay
        Alev0 = A; A *= dpp_mov<0x111, 0xf>(A, 1.0f);  // row_shr:1
        Alev1 = A; A *= dpp_mov<0x112, 0xf>(A, 1.0f);  // row_shr:2
        Alev2 = A; A *= dpp_mov<0x114, 0xf>(A, 1.0f);  // row_shr:4
        Alev3 = A; A *= dpp_mov<0x118, 0xf>(A, 1.0f);  // row_shr:8
        Alev4 = A; A *= dpp_mov<0x142, 0xa>(A, 1.0f);  // bcast15 rows 1,3
        // A = 32-lane inclusive alpha-product per half
        const float Ae_raw = dpp_mov<0x111, 0xf>(A, 1.0f); // shift, old=1
        const float Ae_fix = dpp_mov<0x142, 0xa>(A, 1.0f); // lane15/47 val
        Aexcl = (lh == 16) ? Ae_fix : Ae_raw;  // exclusive alpha-product

        // own wave's total decay Phi over its 128 elems (closed form)
        double np = 1.0, dp = 1.0;
        for (int n = wv * 128; n < wv * 128 + 128; ++n) {
            np *= 1.0 - hdt * (double)n;
            dp *= 1.0 + hdt * (double)(n + 1);
        }
        PhiW = (float)(np / dp);

        c2   = (float)L2E2;
        n2c2 = (float)(-2.0 * L2E2);
    }

    const bool fixlane = (lh == 16);   // lanes 16, 48: row-boundary fix
    const v2f  c2v = (v2f){c2, c2};

    __syncthreads();                   // u_s ready

    // ---- state: m = c2 * h   (h = 0 -> m = 0)
    v2f m01 = (v2f){0.0f, 0.0f}, m23 = (v2f){0.0f, 0.0f};
    float Bf = 0.0f;                   // bcast15 fix reg (rows 0,2 unused)

#pragma unroll 1
    for (int tick = 0; tick < NCH + NW - 1; ++tick) {
        const int ch = tick - wv;      // this wave's chunk index
        if (0 <= ch && ch < NCH) {
            // ---- bulk register loads: u's and the one incoming stream
            float4 u4[CH/4];
            float  Tin[CH];
            {
                const float4* up = (const float4*)&u_s[h][ch * CH];
#pragma unroll
                for (int q = 0; q < CH/4; ++q) u4[q] = up[q];
            }
            if (wv == 0) {
#pragma unroll
                for (int k = 0; k < CH; ++k) Tin[k] = 0.0f;
            } else {
                const float4* bp = (const float4*)&tot_s[wv - 1][h][ch * CH];
#pragma unroll
                for (int q = 0; q < CH/4; ++q) {
                    const float4 v0 = bp[q];
                    Tin[4*q+0] = v0.x; Tin[4*q+1] = v0.y;
                    Tin[4*q+2] = v0.z; Tin[4*q+3] = v0.w;
                }
            }
            float Bacc[CH];

#pragma unroll
            for (int k = 0; k < CH; ++k) {
                const float u = ((const float*)&u4[k>>2])[k&3];
                const v2f  uu = (v2f){u, u};

                // ---- head: w_i = upc_i*u + m_i   (pk)
                const v2f w01 = fma2(upc01, uu, m01);
                const v2f w23 = fma2(upc23, uu, m23);

                // ---- sigmoid bases (pk, -m via neg modifier)
                const v2f bb01 = fma2(ivd01, w01, -m01);
                const v2f bb23 = fma2(ivd23, w23, -m23);

                // scalar triangle seeds
                const float pre = fmaf(t32, w23.x, bb23.y);
                const float g1t = fmaf(t10, w01.x, bb01.y);
                const v2f w0s = (v2f){w01.x, w01.x};
                const v2f w1s = (v2f){w01.y, w01.y};

                // ---- lane-inclusive affine-B (pk dot + h-add)
                const v2f bt = fma2(cB23, w23, cB01 * w01);
                float B = bt.x + bt.y;

                // ---- 32-lane affine scan: 5 fmac_dpp + 2 mov_dpp as
                // chained blocks (order forced by B), packed triangle ops
                // between them fill hazard slots when scheduled there.
                float Tr;
                asm volatile(
                    "s_nop 1\n\t"
                    "v_fmac_f32_dpp %0, %0, %1 row_shr:1 row_mask:0xf bank_mask:0xf bound_ctrl:0"
                    : "+v"(B) : "v"(Alev0));
                v2f tri23 = fma2(c21_31, w1s, (v2f){bb23.x, pre});
                asm volatile(
                    "s_nop 1\n\t"
                    "v_fmac_f32_dpp %0, %0, %1 row_shr:2 row_mask:0xf bank_mask:0xf bound_ctrl:0"
                    : "+v"(B) : "v"(Alev1));
                tri23 = fma2(c20_30, w0s, tri23);
                asm volatile(
                    "s_nop 1\n\t"
                    "v_fmac_f32_dpp %0, %0, %1 row_shr:4 row_mask:0xf bank_mask:0xf bound_ctrl:0"
                    : "+v"(B) : "v"(Alev2));
                const v2f gb01 = (v2f){bb01.x, g1t};
                asm volatile(
                    "s_nop 1\n\t"
                    "v_fmac_f32_dpp %0, %0, %1 row_shr:8 row_mask:0xf bank_mask:0xf bound_ctrl:0"
                    : "+v"(B) : "v"(Alev3));
                asm volatile(
                    "s_nop 1\n\t"
                    "v_fmac_f32_dpp %0, %0, %1 row_bcast:15 row_mask:0xa bank_mask:0xf"
                    : "+v"(B) : "v"(Alev4));
                asm volatile(
                    "s_nop 1\n\t"
                    "v_mov_b32_dpp %0, %1 row_shr:1 row_mask:0xf bank_mask:0xf bound_ctrl:0"
                    : "=v"(Tr) : "v"(B));
                asm volatile(
                    "s_nop 1\n\t"
                    "v_mov_b32_dpp %0, %1 row_bcast:15 row_mask:0xa bank_mask:0xf"
                    : "+v"(Bf) : "v"(B));
                Bacc[k] = B;                        // publish later

                // exclusive prefix: lanes 0,32 -> 0; 16,48 -> lane15/47's B
                const float Tst  = fixlane ? Bf : Tr;
                const float Tent = fmaf(Aexcl, Tin[k], Tst); // lane entry S
                const v2f  TentV = (v2f){Tent, Tent};

                // ---- flattened per-element exponents (pk)
                const v2f g01 = fma2(ka01, TentV, gb01);
                const v2f g23 = fma2(ka23, TentV, tri23);

                // ---- sigmoid tail: clamp, 4 exp2, ONE shared rcp (pk'd)
                const float e0 = EXP2F(fminf(g01.x, 30.0f));
                const float e1 = EXP2F(fminf(g01.y, 30.0f));
                const float e2 = EXP2F(fminf(g23.x, 30.0f));
                const float e3 = EXP2F(fminf(g23.y, 30.0f));
                const v2f q01 = (v2f){e0, e1} + 1.0f;
                const v2f q23 = (v2f){e2, e3} + 1.0f;
                const float p01 = q01.x * q01.y, p23 = q23.x * q23.y;
                const float ip  = __builtin_amdgcn_rcpf(p01 * p23);
                const float tt  = n2c2 * ip;
                const float s01 = tt * p23;            // n2c2 / (q0*q1)
                const float s23 = tt * p01;            // n2c2 / (q2*q3)
                // m_i' = c2 + n2c2/q_i   (pk fma, swapped q via op_sel)
                const v2f q01s = __builtin_shufflevector(q01, q01, 1, 0);
                const v2f q23s = __builtin_shufflevector(q23, q23, 1, 0);
                m01 = fma2((v2f){s01, s01}, q01s, c2v);
                m23 = fma2((v2f){s23, s23}, q23s, c2v);
            }

            // publish composed running totals from BOTH half-ends:
            // lane 31 (batch h=0) and lane 63 (batch h=1)
            if (wv < NW - 1 && lh == 31) {
                float4* tp = (float4*)&tot_s[wv][h][ch * CH];
#pragma unroll
                for (int q = 0; q < CH/4; ++q)
                    tp[q] = make_float4(
                        fmaf(PhiW, Tin[4*q+0], Bacc[4*q+0]),
                        fmaf(PhiW, Tin[4*q+1], Bacc[4*q+1]),
                        fmaf(PhiW, Tin[4*q+2], Bacc[4*q+2]),
                        fmaf(PhiW, Tin[4*q+3], Bacc[4*q+3]));
            }
        }
        __syncthreads();   // one barrier per CHUNK (16 steps)
    }

    // ---- epilogue: h = m/c2; per-half dot(h, C) over 128 elems
    double acc = 0.0;
    {
        const int base = wv * 128 + lh * EPL;
        acc = fma((double)C[base + 0], (double)m01.x, acc);
        acc = fma((double)C[base + 1], (double)m01.y, acc);
        acc = fma((double)C[base + 2], (double)m23.x, acc);
        acc = fma((double)C[base + 3], (double)m23.y, acc);
    }
#pragma unroll
    for (int off = 16; off > 0; off >>= 1)
        acc += __shfl_down(acc, off, 32);     // within 32-lane halves
    if (lh == 0) part_s[wv][h] = acc;
    __syncthreads();
    if (tid < 2 * OUT_DIM) {
        const int q = tid / OUT_DIM, j = tid - q * OUT_DIM;
        double tot = 0.0;
#pragma unroll
        for (int wq = 0; wq < NW; ++wq) tot += part_s[wq][q];
        tot *= 0.34657359027997264;           // 1/c2 = ln2/2, applied once
        out[(b0 + q) * OUT_DIM + j] =
            (float)fma(tot, (double)W[j], (double)bvec[j]);
    }
}

extern "C" void kernel_launch(void* const* d_in, const int* in_sizes, int n_in,
                              void* d_out, int out_size, void* d_ws, size_t ws_size,
                              hipStream_t stream) {
    const float* x  = (const float*)d_in[0];   // (512, 784, 1)
    const float* C  = (const float*)d_in[1];   // (1, 1024)
    const float* W  = (const float*)d_in[2];   // (1, 10)
    const float* bv = (const float*)d_in[3];   // (10,)
    float* out      = (float*)d_out;           // (512, 10)
    hipLaunchKernelGGL(ssm_hippo_scan, dim3(256), dim3(512), 0, stream,
                       x, C, W, bv, out);
}